// Round 13
// baseline (294.914 us; speedup 1.0000x reference)
//
#include <hip/hip_runtime.h>
#include <hip/hip_bf16.h>

#define SLEN 2048
#define DH   64
#define KT   64
#define NTL  32
#define NBH  64

typedef __attribute__((ext_vector_type(8))) short bf16x8;
typedef __attribute__((ext_vector_type(4))) short bf16x4;
typedef __attribute__((ext_vector_type(4))) float f32x4;

__device__ __forceinline__ short f2bf_hw(float f) {
    union { __hip_bfloat16 b; short s; } u;
    u.b = __float2bfloat16(f);            // HW RNE convert
    return u.s;
}
__device__ __forceinline__ short2 f2bf2_hw(float a, float b) {
    union { __hip_bfloat162 b2; short2 s2; } u;
    u.b2 = __float22bfloat162_rn(float2{a, b});   // v_cvt_pk_bf16_f32
    return u.s2;
}
__device__ __forceinline__ float bf2f(short s) {
    union { unsigned u; float f; } v;
    v.u = ((unsigned)(unsigned short)s) << 16;
    return v.f;
}

// legacy bit-op convert (fallback kernel only)
__device__ __forceinline__ short f2bf(float f) {
    union { float f; unsigned u; } v; v.f = f;
    unsigned u = v.u;
    u += 0x7fff + ((u >> 16) & 1);
    return (short)(u >> 16);
}

// ==== kernel A: pass 1 (row sum-exp) + distributed K/V bf16 conversion ====
__global__ __launch_bounds__(256, 3)
void pass1_kernel(const float* __restrict__ Q, const float* __restrict__ K,
                  const float* __restrict__ V,
                  short* __restrict__ Kw, short* __restrict__ Vt,
                  float* __restrict__ c2g)
{
    __shared__ __align__(16) short lk[2][KT][72];
    __shared__ __align__(16) short lvt[KT][72];

    const int tid = threadIdx.x;
    const int w = tid >> 6, lane = tid & 63, g = lane >> 4, lc = lane & 15;

    const int bid = (int)blockIdx.x;               // T1 XCD swizzle
    const int wg = (bid & 7) * 256 + (bid >> 3);
    const int qt = wg & 31, bh = wg >> 5;

    const int r = tid >> 2;            // staging row 0..63
    const int c = (tid & 3) << 4;      // staging col group (16 elems)

    const float* Kbh = K + (size_t)bh * SLEN * DH;
    short* Kwp = Kw + (size_t)bh * SLEN * DH;

    // ---- V side-duty: convert+transpose V tile qt -> Vt (each (bh,tile) once) ----
    {
        const float4* src = (const float4*)(V + ((size_t)bh * SLEN + qt * KT + r) * DH + c);
        #pragma unroll
        for (int q4 = 0; q4 < 4; ++q4) {
            float4 fv = src[q4];
            short2 p0 = f2bf2_hw(fv.x, fv.y);
            short2 p1 = f2bf2_hw(fv.z, fv.w);
            lvt[c + q4*4 + 0][r] = p0.x;
            lvt[c + q4*4 + 1][r] = p0.y;
            lvt[c + q4*4 + 2][r] = p1.x;
            lvt[c + q4*4 + 3][r] = p1.y;
        }
        __syncthreads();
        short* dst = Vt + (size_t)bh * DH * SLEN + (size_t)r * SLEN + qt * KT + c;
        *(bf16x8*)dst       = *(const bf16x8*)&lvt[r][c];      // cached: B re-reads
        *(bf16x8*)(dst + 8) = *(const bf16x8*)&lvt[r][c + 8];
    }

    // ---- Q fragments, 0.125 scale folded (exact pow2) ----
    bf16x8 qf[2];
    {
        const float* qsrc = Q + ((size_t)bh * SLEN + qt * KT + w * 16 + lc) * DH + g * 8;
        #pragma unroll
        for (int s = 0; s < 2; ++s)
            #pragma unroll
            for (int j = 0; j < 4; ++j) {
                short2 p = f2bf2_hw(qsrc[s * 32 + 2 * j] * 0.125f,
                                    qsrc[s * 32 + 2 * j + 1] * 0.125f);
                qf[s][2 * j]     = p.x;
                qf[s][2 * j + 1] = p.y;
            }
    }

    // ---- pass 1: on-the-fly K convert staging (per-ROW addressing = store layout) ----
    float lsum[4] = {0.f, 0.f, 0.f, 0.f};
    {   // prologue: tile 0 — thread owns row r, cols c..c+15
        const float4* src = (const float4*)(Kbh + (size_t)r * DH + c);
        alignas(16) short tmp[16];
        #pragma unroll
        for (int q4 = 0; q4 < 4; ++q4) {
            float4 fv = src[q4];
            *(short2*)&tmp[q4*4]     = f2bf2_hw(fv.x, fv.y);
            *(short2*)&tmp[q4*4 + 2] = f2bf2_hw(fv.z, fv.w);
        }
        *(bf16x8*)&lk[0][r][c]     = *(const bf16x8*)&tmp[0];
        *(bf16x8*)&lk[0][r][c + 8] = *(const bf16x8*)&tmp[8];
    }
    __syncthreads();

    for (int t = 0; t < NTL; ++t) {
        float4 kr[4];
        const bool pre = (t + 1 < NTL);
        if (pre) {
            const float4* src = (const float4*)(Kbh + (size_t)((t + 1) * KT + r) * DH + c);
            #pragma unroll
            for (int q4 = 0; q4 < 4; ++q4) kr[q4] = src[q4];
        }

        f32x4 acc[4];
        #pragma unroll
        for (int nt = 0; nt < 4; ++nt) acc[nt] = (f32x4){0.f,0.f,0.f,0.f};
        #pragma unroll
        for (int s = 0; s < 2; ++s)
            #pragma unroll
            for (int nt = 0; nt < 4; ++nt) {
                bf16x8 kf = *(const bf16x8*)&lk[t & 1][nt * 16 + lc][s * 32 + g * 8];
                acc[nt] = __builtin_amdgcn_mfma_f32_16x16x32_bf16(qf[s], kf, acc[nt], 0, 0, 0);
            }
        #pragma unroll
        for (int nt = 0; nt < 4; ++nt)
            #pragma unroll
            for (int e = 0; e < 4; ++e)
                lsum[e] += __expf(acc[nt][e]);

        // K side-duty: block qt writes bf16 K tile t==qt (slot stable until barrier)
        if (t == qt) {
            bf16x8 a  = *(const bf16x8*)&lk[t & 1][r][c];
            bf16x8 b2 = *(const bf16x8*)&lk[t & 1][r][c + 8];
            short* kd = Kwp + t * (KT * DH) + r * DH + c;
            *(bf16x8*)kd       = a;        // cached: B re-reads
            *(bf16x8*)(kd + 8) = b2;
        }

        if (pre) {
            alignas(16) short tmp[16];
            #pragma unroll
            for (int q4 = 0; q4 < 4; ++q4) {
                float4 fv = kr[q4];
                *(short2*)&tmp[q4*4]     = f2bf2_hw(fv.x, fv.y);
                *(short2*)&tmp[q4*4 + 2] = f2bf2_hw(fv.z, fv.w);
            }
            *(bf16x8*)&lk[(t + 1) & 1][r][c]     = *(const bf16x8*)&tmp[0];
            *(bf16x8*)&lk[(t + 1) & 1][r][c + 8] = *(const bf16x8*)&tmp[8];
        }
        __syncthreads();
    }

    // c2 = -ln(rowsum) per row, one writer lane per row
    #pragma unroll
    for (int e = 0; e < 4; ++e) {
        float s = lsum[e];
        s += __shfl_xor(s, 1); s += __shfl_xor(s, 2);
        s += __shfl_xor(s, 4); s += __shfl_xor(s, 8);
        if (lc == 0)
            c2g[(size_t)wg * 64 + w * 16 + 4 * g + e] = -__logf(s);
    }
}

// ==== kernel B: pass 2 (recompute S, write attn, PV) — R11 pass-2 verbatim ====
__global__ __launch_bounds__(256, 3)
void pass2_kernel(const float* __restrict__ Q, const short* __restrict__ Kw,
                  const short* __restrict__ Vt, const float* __restrict__ c2g,
                  float* __restrict__ out, float* __restrict__ attn)
{
    __shared__ __align__(16) short lkv[4][KT][72];
    __shared__ __align__(16) short lp[4][16][72];
    __shared__ float lc2[64];

    const int tid = threadIdx.x;
    const int w = tid >> 6, lane = tid & 63, g = lane >> 4, lc = lane & 15;

    const int bid = (int)blockIdx.x;               // T1 XCD swizzle
    const int wg = (bid & 7) * 256 + (bid >> 3);
    const int qt = wg & 31, bh = wg >> 5;

    const short* Ktile = Kw + (size_t)bh * SLEN * DH;
    const short* Vbh   = Vt + (size_t)bh * DH * SLEN;
    float* outb  = out  + ((size_t)bh * SLEN + qt * KT) * DH;
    float* attnb = attn + ((size_t)bh * SLEN + qt * KT) * SLEN;

    const int srow = tid >> 3;        // 0..31
    const int scol = (tid & 7) * 8;   // 0..56
    const int rr = lane >> 4;         // 0..3
    const int cc = (lane & 15) * 4;   // 0..60

    if (tid < 64) lc2[tid] = c2g[(size_t)wg * 64 + tid];

    bf16x8 qf[2];
    {
        const float* qsrc = Q + ((size_t)bh * SLEN + qt * KT + w * 16 + lc) * DH + g * 8;
        #pragma unroll
        for (int s = 0; s < 2; ++s)
            #pragma unroll
            for (int j = 0; j < 4; ++j) {
                short2 p = f2bf2_hw(qsrc[s * 32 + 2 * j] * 0.125f,
                                    qsrc[s * 32 + 2 * j + 1] * 0.125f);
                qf[s][2 * j]     = p.x;
                qf[s][2 * j + 1] = p.y;
            }
    }

    f32x4 oacc[4];
    #pragma unroll
    for (int nt = 0; nt < 4; ++nt) oacc[nt] = (f32x4){0.f,0.f,0.f,0.f};

    {   // prologue: stage K + V tile 0
        const short* ks = Ktile;
        const short* vs = Vbh;
        bf16x8 k0 = *(const bf16x8*)(ks + tid * 8);
        bf16x8 k1 = *(const bf16x8*)(ks + (tid + 256) * 8);
        bf16x8 v0 = *(const bf16x8*)(vs + (size_t)srow * SLEN + scol);
        bf16x8 v1 = *(const bf16x8*)(vs + (size_t)(srow + 32) * SLEN + scol);
        *(bf16x8*)&lkv[0][srow][scol]      = k0;
        *(bf16x8*)&lkv[0][srow + 32][scol] = k1;
        *(bf16x8*)&lkv[2][srow][scol]      = v0;
        *(bf16x8*)&lkv[2][srow + 32][scol] = v1;
    }
    __syncthreads();

    float c2[4];
    #pragma unroll
    for (int e = 0; e < 4; ++e) c2[e] = lc2[w * 16 + 4 * g + e];

    for (int t = 0; t < NTL; ++t) {
        bf16x8 k0, k1, v0, v1;
        const bool pre = (t + 1 < NTL);
        if (pre) {
            const short* ks = Ktile + (t + 1) * (KT * DH);
            const short* vs = Vbh + (t + 1) * KT;
            k0 = *(const bf16x8*)(ks + tid * 8);
            k1 = *(const bf16x8*)(ks + (tid + 256) * 8);
            v0 = *(const bf16x8*)(vs + (size_t)srow * SLEN + scol);
            v1 = *(const bf16x8*)(vs + (size_t)(srow + 32) * SLEN + scol);
        }

        f32x4 acc[4];
        #pragma unroll
        for (int nt = 0; nt < 4; ++nt) acc[nt] = (f32x4){0.f,0.f,0.f,0.f};
        #pragma unroll
        for (int s = 0; s < 2; ++s)
            #pragma unroll
            for (int nt = 0; nt < 4; ++nt) {
                bf16x8 kf = *(const bf16x8*)&lkv[t & 1][nt * 16 + lc][s * 32 + g * 8];
                acc[nt] = __builtin_amdgcn_mfma_f32_16x16x32_bf16(qf[s], kf, acc[nt], 0, 0, 0);
            }

        // P = exp(s + ln(1/l)) -> bf16 into per-wave LDS
        #pragma unroll
        for (int nt = 0; nt < 4; ++nt)
            #pragma unroll
            for (int e = 0; e < 4; ++e) {
                float p = __expf(acc[nt][e] + c2[e]);
                lp[w][4 * g + e][nt * 16 + lc] = f2bf_hw(p);
            }

        // attn store, issued before PV: instr j = 4 rows x 256B contiguous
        #pragma unroll
        for (int j = 0; j < 4; ++j) {
            const int row = j * 4 + rr;
            bf16x4 ps = *(const bf16x4*)&lp[w][row][cc];
            f32x4 qv = { bf2f(ps[0]), bf2f(ps[1]), bf2f(ps[2]), bf2f(ps[3]) };
            __builtin_nontemporal_store(
                qv, (f32x4*)(attnb + (size_t)(w * 16 + row) * SLEN + t * KT + cc));
        }

        // PV from V^T tile (slots 2/3)
        #pragma unroll
        for (int kc = 0; kc < 2; ++kc) {
            bf16x8 pf = *(const bf16x8*)&lp[w][lc][kc * 32 + g * 8];
            #pragma unroll
            for (int nt = 0; nt < 4; ++nt) {
                bf16x8 vf = *(const bf16x8*)&lkv[2 + (t & 1)][nt * 16 + lc][kc * 32 + g * 8];
                oacc[nt] = __builtin_amdgcn_mfma_f32_16x16x32_bf16(pf, vf, oacc[nt], 0, 0, 0);
            }
        }

        if (pre) {
            *(bf16x8*)&lkv[(t + 1) & 1][srow][scol]      = k0;
            *(bf16x8*)&lkv[(t + 1) & 1][srow + 32][scol] = k1;
            *(bf16x8*)&lkv[2 + ((t + 1) & 1)][srow][scol]      = v0;
            *(bf16x8*)&lkv[2 + ((t + 1) & 1)][srow + 32][scol] = v1;
        }
        __syncthreads();
    }

    // epilogue: out via LDS bounce, dense per-instruction stores
    {
        float* lds_o = (float*)lkv;
        #pragma unroll
        for (int nt = 0; nt < 4; ++nt)
            #pragma unroll
            for (int e = 0; e < 4; ++e)
                lds_o[(w * 16 + 4 * g + e) * 72 + nt * 16 + lc] = oacc[nt][e];
        __syncthreads();
        #pragma unroll
        for (int j = 0; j < 4; ++j) {
            const int row = j * 16 + (tid >> 4);
            const int col = (tid & 15) * 4;
            f32x4 v = *(f32x4*)&lds_o[row * 72 + col];
            __builtin_nontemporal_store(v, (f32x4*)(outb + (size_t)row * DH + col));
        }
    }
}

// ---- fallback (R2 kernel verbatim, used only if d_ws is too small) ----
__global__ __launch_bounds__(256, 3)
void sdpa_fallback(const float* __restrict__ Q, const float* __restrict__ K,
                   const float* __restrict__ V, float* __restrict__ out,
                   float* __restrict__ attn)
{
    __shared__ __align__(16) short lk[2][KT][72];
    __shared__ __align__(16) short lv[2][DH * 72];
    __shared__ __align__(16) short lp[4][16][72];

    const int tid = threadIdx.x;
    const int w = tid >> 6, lane = tid & 63, g = lane >> 4, lc = lane & 15;
    const int bid = (int)blockIdx.x;
    const int wg = (bid & 7) * 256 + (bid >> 3);
    const int qt = wg & 31, bh = wg >> 5;

    const float*  Qb  = Q + ((size_t)bh * SLEN + qt * 64) * DH;
    const float4* Kb4 = (const float4*)(K + (size_t)bh * SLEN * DH);
    const float4* Vb4 = (const float4*)(V + (size_t)bh * SLEN * DH);
    float* outb  = out  + ((size_t)bh * SLEN + qt * 64) * DH;
    float* attnb = attn + ((size_t)bh * SLEN + qt * 64) * SLEN;

    const int sr = (tid >> 4);
    const int sc = (tid & 15) * 4;

    bf16x8 qf[2];
    {
        const float* qsrc = Qb + (w * 16 + lc) * DH + g * 8;
        #pragma unroll
        for (int s = 0; s < 2; ++s)
            #pragma unroll
            for (int j = 0; j < 8; ++j)
                qf[s][j] = f2bf(qsrc[s * 32 + j] * 0.125f);
    }

    float lsum[4] = {0.f, 0.f, 0.f, 0.f};
    {
        float4 kr[4];
        #pragma unroll
        for (int q4 = 0; q4 < 4; ++q4) kr[q4] = Kb4[q4 * 256 + tid];
        #pragma unroll
        for (int q4 = 0; q4 < 4; ++q4) {
            short4 s4 = { f2bf(kr[q4].x), f2bf(kr[q4].y), f2bf(kr[q4].z), f2bf(kr[q4].w) };
            *(short4*)&lk[0][q4 * 16 + sr][sc] = s4;
        }
    }
    __syncthreads();
    for (int t = 0; t < NTL; ++t) {
        float4 kr[4];
        const bool pre = (t + 1 < NTL);
        if (pre) {
            const float4* src = Kb4 + (size_t)(t + 1) * 1024;
            #pragma unroll
            for (int q4 = 0; q4 < 4; ++q4) kr[q4] = src[q4 * 256 + tid];
        }
        f32x4 acc[4];
        #pragma unroll
        for (int nt = 0; nt < 4; ++nt) acc[nt] = (f32x4){0.f,0.f,0.f,0.f};
        #pragma unroll
        for (int s = 0; s < 2; ++s)
            #pragma unroll
            for (int nt = 0; nt < 4; ++nt) {
                bf16x8 kf = *(const bf16x8*)&lk[t & 1][nt * 16 + lc][s * 32 + g * 8];
                acc[nt] = __builtin_amdgcn_mfma_f32_16x16x32_bf16(qf[s], kf, acc[nt], 0, 0, 0);
            }
        #pragma unroll
        for (int nt = 0; nt < 4; ++nt)
            #pragma unroll
            for (int e = 0; e < 4; ++e)
                lsum[e] += __expf(acc[nt][e]);
        if (pre) {
            #pragma unroll
            for (int q4 = 0; q4 < 4; ++q4) {
                short4 s4 = { f2bf(kr[q4].x), f2bf(kr[q4].y), f2bf(kr[q4].z), f2bf(kr[q4].w) };
                *(short4*)&lk[(t + 1) & 1][q4 * 16 + sr][sc] = s4;
            }
        }
        __syncthreads();
    }
    float c2[4];
    #pragma unroll
    for (int e = 0; e < 4; ++e) {
        float s = lsum[e];
        s += __shfl_xor(s, 1); s += __shfl_xor(s, 2);
        s += __shfl_xor(s, 4); s += __shfl_xor(s, 8);
        c2[e] = -__logf(s);
    }
    f32x4 oacc[4];
    #pragma unroll
    for (int nt = 0; nt < 4; ++nt) oacc[nt] = (f32x4){0.f,0.f,0.f,0.f};
    {
        float4 kr[4], vr[4];
        #pragma unroll
        for (int q4 = 0; q4 < 4; ++q4) { kr[q4] = Kb4[q4 * 256 + tid]; vr[q4] = Vb4[q4 * 256 + tid]; }
        #pragma unroll
        for (int q4 = 0; q4 < 4; ++q4) {
            short4 s4 = { f2bf(kr[q4].x), f2bf(kr[q4].y), f2bf(kr[q4].z), f2bf(kr[q4].w) };
            *(short4*)&lk[0][q4 * 16 + sr][sc] = s4;
            float fv[4] = { vr[q4].x, vr[q4].y, vr[q4].z, vr[q4].w };
            #pragma unroll
            for (int j = 0; j < 4; ++j) {
                int d = sc + j;
                int idx = (d * 72 + q4 * 16 + sr) ^ (((d >> 3) & 7) << 3);
                lv[0][idx] = f2bf(fv[j]);
            }
        }
    }
    __syncthreads();
    for (int t = 0; t < NTL; ++t) {
        float4 kr[4], vr[4];
        const bool pre = (t + 1 < NTL);
        if (pre) {
            const float4* ks = Kb4 + (size_t)(t + 1) * 1024;
            const float4* vs = Vb4 + (size_t)(t + 1) * 1024;
            #pragma unroll
            for (int q4 = 0; q4 < 4; ++q4) { kr[q4] = ks[q4 * 256 + tid]; vr[q4] = vs[q4 * 256 + tid]; }
        }
        f32x4 acc[4];
        #pragma unroll
        for (int nt = 0; nt < 4; ++nt) acc[nt] = (f32x4){0.f,0.f,0.f,0.f};
        #pragma unroll
        for (int s = 0; s < 2; ++s)
            #pragma unroll
            for (int nt = 0; nt < 4; ++nt) {
                bf16x8 kf = *(const bf16x8*)&lk[t & 1][nt * 16 + lc][s * 32 + g * 8];
                acc[nt] = __builtin_amdgcn_mfma_f32_16x16x32_bf16(qf[s], kf, acc[nt], 0, 0, 0);
            }
        #pragma unroll
        for (int nt = 0; nt < 4; ++nt)
            #pragma unroll
            for (int e = 0; e < 4; ++e) {
                float p = __expf(acc[nt][e] + c2[e]);
                attnb[(size_t)(w * 16 + 4 * g + e) * SLEN + t * KT + nt * 16 + lc] = p;
                lp[w][4 * g + e][nt * 16 + lc] = f2bf(p);
            }
        const short* lvb = lv[t & 1];
        #pragma unroll
        for (int kc = 0; kc < 2; ++kc) {
            bf16x8 pf = *(const bf16x8*)&lp[w][lc][kc * 32 + g * 8];
            #pragma unroll
            for (int nt = 0; nt < 4; ++nt) {
                int d0 = nt * 16 + lc;
                int idx = (d0 * 72 + kc * 32 + g * 8) ^ (((d0 >> 3) & 7) << 3);
                bf16x8 vfrag = *(const bf16x8*)&lvb[idx];
                oacc[nt] = __builtin_amdgcn_mfma_f32_16x16x32_bf16(pf, vfrag, oacc[nt], 0, 0, 0);
            }
        }
        if (pre) {
            #pragma unroll
            for (int q4 = 0; q4 < 4; ++q4) {
                short4 s4 = { f2bf(kr[q4].x), f2bf(kr[q4].y), f2bf(kr[q4].z), f2bf(kr[q4].w) };
                *(short4*)&lk[(t + 1) & 1][q4 * 16 + sr][sc] = s4;
                float fv[4] = { vr[q4].x, vr[q4].y, vr[q4].z, vr[q4].w };
                #pragma unroll
                for (int j = 0; j < 4; ++j) {
                    int d = sc + j;
                    int idx = (d * 72 + q4 * 16 + sr) ^ (((d >> 3) & 7) << 3);
                    lv[(t + 1) & 1][idx] = f2bf(fv[j]);
                }
            }
        }
        __syncthreads();
    }
    #pragma unroll
    for (int nt = 0; nt < 4; ++nt)
        #pragma unroll
        for (int e = 0; e < 4; ++e)
            outb[(w * 16 + 4 * g + e) * DH + nt * 16 + lc] = oacc[nt][e];
}

extern "C" void kernel_launch(void* const* d_in, const int* in_sizes, int n_in,
                              void* d_out, int out_size, void* d_ws, size_t ws_size,
                              hipStream_t stream) {
    const float* Q = (const float*)d_in[0];
    const float* K = (const float*)d_in[1];
    const float* V = (const float*)d_in[2];
    float* out  = (float*)d_out;
    float* attn = out + (size_t)NBH * SLEN * DH;   // out first, then attn (return order)

    const size_t nelem = (size_t)NBH * SLEN * DH;  // 8388608 per tensor
    const size_t need = 2 * nelem * sizeof(short) + (size_t)2048 * 64 * sizeof(float);
    if (ws_size >= need) {
        short* Kw = (short*)d_ws;
        short* Vt = Kw + nelem;
        float* c2g = (float*)(Vt + nelem);
        pass1_kernel<<<dim3(2048), dim3(256), 0, stream>>>(Q, K, V, Kw, Vt, c2g);
        pass2_kernel<<<dim3(2048), dim3(256), 0, stream>>>(Q, Kw, Vt, c2g, out, attn);
    } else {
        sdpa_fallback<<<dim3(2048), dim3(256), 0, stream>>>(Q, K, V, out, attn);
    }
}

// Round 14
// 247.370 us; speedup vs baseline: 1.1922x; 1.1922x over previous
//
#include <hip/hip_runtime.h>
#include <hip/hip_bf16.h>

#define SLEN 2048
#define DH   64
#define KT   64
#define NTL  32
#define NBH  64

typedef __attribute__((ext_vector_type(8))) short bf16x8;
typedef __attribute__((ext_vector_type(4))) short bf16x4;
typedef __attribute__((ext_vector_type(4))) float f32x4;

__device__ __forceinline__ short f2bf_hw(float f) {
    union { __hip_bfloat16 b; short s; } u;
    u.b = __float2bfloat16(f);            // HW RNE convert
    return u.s;
}
__device__ __forceinline__ short2 f2bf2_hw(float a, float b) {
    union { __hip_bfloat162 b2; short2 s2; } u;
    u.b2 = __float22bfloat162_rn(float2{a, b});   // v_cvt_pk_bf16_f32
    return u.s2;
}
__device__ __forceinline__ float bf2f(short s) {
    union { unsigned u; float f; } v;
    v.u = ((unsigned)(unsigned short)s) << 16;
    return v.f;
}

// legacy bit-op convert (fallback kernel only)
__device__ __forceinline__ short f2bf(float f) {
    union { float f; unsigned u; } v; v.f = f;
    unsigned u = v.u;
    u += 0x7fff + ((u >> 16) & 1);
    return (short)(u >> 16);
}

// ---- one-time convert: K -> bf16 row-major; V -> bf16 transposed [d][s] ----
__global__ __launch_bounds__(256)
void conv_kernel(const float* __restrict__ K, const float* __restrict__ V,
                 short* __restrict__ Kw, short* __restrict__ Vt)
{
    __shared__ short lvt[DH][72];
    const int tid = threadIdx.x;
    const int blk = (int)blockIdx.x;
    const int bh = blk >> 5, t = blk & 31;
    const int r = tid >> 2;            // row in 64-tile
    const int c = (tid & 3) << 4;      // col group (16 elems)

    if (blockIdx.y == 1) {             // V: transpose via LDS
        const float4* src = (const float4*)(V + ((size_t)bh * SLEN + t * KT + r) * DH + c);
        #pragma unroll
        for (int q4 = 0; q4 < 4; ++q4) {
            float4 fv = src[q4];
            short2 p0 = f2bf2_hw(fv.x, fv.y);
            short2 p1 = f2bf2_hw(fv.z, fv.w);
            lvt[c + q4*4 + 0][r] = p0.x;
            lvt[c + q4*4 + 1][r] = p0.y;
            lvt[c + q4*4 + 2][r] = p1.x;
            lvt[c + q4*4 + 3][r] = p1.y;
        }
        __syncthreads();
        short* dst = Vt + (size_t)bh * DH * SLEN + (size_t)r * SLEN + t * KT + c;
        *(bf16x8*)dst       = *(const bf16x8*)&lvt[r][c];
        *(bf16x8*)(dst + 8) = *(const bf16x8*)&lvt[r][c + 8];
    } else {                           // K: straight convert
        size_t off = ((size_t)bh * SLEN + t * KT + r) * DH + c;
        const float4* src = (const float4*)(K + off);
        alignas(16) short tmp[16];
        #pragma unroll
        for (int q4 = 0; q4 < 4; ++q4) {
            float4 fv = src[q4];
            *(short2*)&tmp[q4*4]     = f2bf2_hw(fv.x, fv.y);
            *(short2*)&tmp[q4*4 + 2] = f2bf2_hw(fv.z, fv.w);
        }
        *(bf16x8*)(Kw + off)     = *(const bf16x8*)&tmp[0];
        *(bf16x8*)(Kw + off + 8) = *(const bf16x8*)&tmp[8];
    }
}

// ---- main: R10 + pass-1 2-tile-deep double buffer (4 LDS slots, 16 barriers) ----
__global__ __launch_bounds__(256, 3)
void sdpa_main(const float* __restrict__ Q, const short* __restrict__ Kw,
               const short* __restrict__ Vt, float* __restrict__ out,
               float* __restrict__ attn)
{
    // 4 tile slots: pass 1 rotates K tiles through all 4 (slot = t & 3);
    // pass 2 uses slots 0/1 for K and 2/3 for V.
    __shared__ __align__(16) short lkv[4][KT][72];
    __shared__ __align__(16) short lp[4][16][72];

    const int tid = threadIdx.x;
    const int w = tid >> 6, lane = tid & 63, g = lane >> 4, lc = lane & 15;

    const int bid = (int)blockIdx.x;               // T1 XCD swizzle (2048 % 8 == 0)
    const int wg = (bid & 7) * 256 + (bid >> 3);
    const int qt = wg & 31, bh = wg >> 5;

    const short* Ktile = Kw + (size_t)bh * SLEN * DH;
    const short* Vbh   = Vt + (size_t)bh * DH * SLEN;
    float* outb  = out  + ((size_t)bh * SLEN + qt * KT) * DH;
    float* attnb = attn + ((size_t)bh * SLEN + qt * KT) * SLEN;

    // staging decomposition: 16B chunk i -> row i>>3, col (i&7)*8
    const int srow = tid >> 3;        // 0..31
    const int scol = (tid & 7) * 8;   // 0..56

    // attn-store decomposition: instr j -> rows j*4+rr, 256B contiguous per row
    const int rr = lane >> 4;         // 0..3
    const int cc = (lane & 15) * 4;   // 0..60

    // Q fragments direct from fp32 global, 0.125 scale folded (EXACT pow2)
    bf16x8 qf[2];
    {
        const float* qsrc = Q + ((size_t)bh * SLEN + qt * KT + w * 16 + lc) * DH + g * 8;
        #pragma unroll
        for (int s = 0; s < 2; ++s)
            #pragma unroll
            for (int j = 0; j < 4; ++j) {
                short2 p = f2bf2_hw(qsrc[s * 32 + 2 * j] * 0.125f,
                                    qsrc[s * 32 + 2 * j + 1] * 0.125f);
                qf[s][2 * j]     = p.x;
                qf[s][2 * j + 1] = p.y;
            }
    }

    // ================= pass 1: per-lane sum-exp, 2 tiles per barrier =================
    float lsum[4] = {0.f, 0.f, 0.f, 0.f};
    {   // prologue: stage K tiles 0,1 -> slots 0,1
        #pragma unroll
        for (int p = 0; p < 2; ++p) {
            const short* ks = Ktile + p * (KT * DH);
            bf16x8 k0 = *(const bf16x8*)(ks + tid * 8);
            bf16x8 k1 = *(const bf16x8*)(ks + (tid + 256) * 8);
            *(bf16x8*)&lkv[p][srow][scol]      = k0;
            *(bf16x8*)&lkv[p][srow + 32][scol] = k1;
        }
    }
    __syncthreads();

    for (int t = 0; t < NTL; t += 2) {
        bf16x8 ka0, ka1, kb0, kb1;
        const bool pre = (t + 2 < NTL);
        if (pre) {   // issue 4 prefetch loads early (tiles t+2, t+3)
            const short* ksa = Ktile + (t + 2) * (KT * DH);
            const short* ksb = Ktile + (t + 3) * (KT * DH);
            ka0 = *(const bf16x8*)(ksa + tid * 8);
            ka1 = *(const bf16x8*)(ksa + (tid + 256) * 8);
            kb0 = *(const bf16x8*)(ksb + tid * 8);
            kb1 = *(const bf16x8*)(ksb + (tid + 256) * 8);
        }

        // compute tiles t and t+1 from slots (t&3) and ((t+1)&3)
        #pragma unroll
        for (int u = 0; u < 2; ++u) {
            const int slot = (t + u) & 3;
            f32x4 acc[4];
            #pragma unroll
            for (int nt = 0; nt < 4; ++nt) acc[nt] = (f32x4){0.f,0.f,0.f,0.f};
            #pragma unroll
            for (int s = 0; s < 2; ++s)
                #pragma unroll
                for (int nt = 0; nt < 4; ++nt) {
                    bf16x8 kf = *(const bf16x8*)&lkv[slot][nt * 16 + lc][s * 32 + g * 8];
                    acc[nt] = __builtin_amdgcn_mfma_f32_16x16x32_bf16(qf[s], kf, acc[nt], 0, 0, 0);
                }
            #pragma unroll
            for (int nt = 0; nt < 4; ++nt)
                #pragma unroll
                for (int e = 0; e < 4; ++e)
                    lsum[e] += __expf(acc[nt][e]);
        }

        if (pre) {   // write tiles t+2, t+3 into the slots just freed
            *(bf16x8*)&lkv[(t + 2) & 3][srow][scol]      = ka0;
            *(bf16x8*)&lkv[(t + 2) & 3][srow + 32][scol] = ka1;
            *(bf16x8*)&lkv[(t + 3) & 3][srow][scol]      = kb0;
            *(bf16x8*)&lkv[(t + 3) & 3][srow + 32][scol] = kb1;
        }
        __syncthreads();
    }

    float c2[4];
    #pragma unroll
    for (int e = 0; e < 4; ++e) {
        float s = lsum[e];
        s += __shfl_xor(s, 1); s += __shfl_xor(s, 2);
        s += __shfl_xor(s, 4); s += __shfl_xor(s, 8);
        c2[e] = -__logf(s);    // p = exp(s + ln(1/l))
    }

    // ================= pass 2: recompute S, write attn, PV =================
    f32x4 oacc[4];
    #pragma unroll
    for (int nt = 0; nt < 4; ++nt) oacc[nt] = (f32x4){0.f,0.f,0.f,0.f};

    __syncthreads();   // ensure pass-1 reads done before overwriting slots
    {   // prologue: stage K + V tile 0
        const short* ks = Ktile;
        const short* vs = Vbh;
        bf16x8 k0 = *(const bf16x8*)(ks + tid * 8);
        bf16x8 k1 = *(const bf16x8*)(ks + (tid + 256) * 8);
        bf16x8 v0 = *(const bf16x8*)(vs + (size_t)srow * SLEN + scol);
        bf16x8 v1 = *(const bf16x8*)(vs + (size_t)(srow + 32) * SLEN + scol);
        *(bf16x8*)&lkv[0][srow][scol]      = k0;
        *(bf16x8*)&lkv[0][srow + 32][scol] = k1;
        *(bf16x8*)&lkv[2][srow][scol]      = v0;
        *(bf16x8*)&lkv[2][srow + 32][scol] = v1;
    }
    __syncthreads();

    for (int t = 0; t < NTL; ++t) {
        bf16x8 k0, k1, v0, v1;
        const bool pre = (t + 1 < NTL);
        if (pre) {
            const short* ks = Ktile + (t + 1) * (KT * DH);
            const short* vs = Vbh + (t + 1) * KT;
            k0 = *(const bf16x8*)(ks + tid * 8);
            k1 = *(const bf16x8*)(ks + (tid + 256) * 8);
            v0 = *(const bf16x8*)(vs + (size_t)srow * SLEN + scol);
            v1 = *(const bf16x8*)(vs + (size_t)(srow + 32) * SLEN + scol);
        }

        f32x4 acc[4];
        #pragma unroll
        for (int nt = 0; nt < 4; ++nt) acc[nt] = (f32x4){0.f,0.f,0.f,0.f};
        #pragma unroll
        for (int s = 0; s < 2; ++s)
            #pragma unroll
            for (int nt = 0; nt < 4; ++nt) {
                bf16x8 kf = *(const bf16x8*)&lkv[t & 1][nt * 16 + lc][s * 32 + g * 8];
                acc[nt] = __builtin_amdgcn_mfma_f32_16x16x32_bf16(qf[s], kf, acc[nt], 0, 0, 0);
            }

        // P = exp(s + ln(1/l)) -> bf16 into per-wave LDS
        #pragma unroll
        for (int nt = 0; nt < 4; ++nt)
            #pragma unroll
            for (int e = 0; e < 4; ++e) {
                float p = __expf(acc[nt][e] + c2[e]);
                lp[w][4 * g + e][nt * 16 + lc] = f2bf_hw(p);
            }

        // attn store, issued before PV: instr j = 4 rows x 256B contiguous
        #pragma unroll
        for (int j = 0; j < 4; ++j) {
            const int row = j * 4 + rr;
            bf16x4 ps = *(const bf16x4*)&lp[w][row][cc];
            f32x4 qv = { bf2f(ps[0]), bf2f(ps[1]), bf2f(ps[2]), bf2f(ps[3]) };
            __builtin_nontemporal_store(
                qv, (f32x4*)(attnb + (size_t)(w * 16 + row) * SLEN + t * KT + cc));
        }

        // PV from V^T tile in LDS (slots 2/3)
        #pragma unroll
        for (int kc = 0; kc < 2; ++kc) {
            bf16x8 pf = *(const bf16x8*)&lp[w][lc][kc * 32 + g * 8];
            #pragma unroll
            for (int nt = 0; nt < 4; ++nt) {
                bf16x8 vf = *(const bf16x8*)&lkv[2 + (t & 1)][nt * 16 + lc][kc * 32 + g * 8];
                oacc[nt] = __builtin_amdgcn_mfma_f32_16x16x32_bf16(pf, vf, oacc[nt], 0, 0, 0);
            }
        }

        if (pre) {
            *(bf16x8*)&lkv[(t + 1) & 1][srow][scol]      = k0;
            *(bf16x8*)&lkv[(t + 1) & 1][srow + 32][scol] = k1;
            *(bf16x8*)&lkv[2 + ((t + 1) & 1)][srow][scol]      = v0;
            *(bf16x8*)&lkv[2 + ((t + 1) & 1)][srow + 32][scol] = v1;
        }
        __syncthreads();
    }

    // ---- epilogue: out via LDS bounce, dense per-instruction stores ----
    {
        float* lds_o = (float*)lkv;   // 64 rows x 72 floats = 18432 B, fits
        #pragma unroll
        for (int nt = 0; nt < 4; ++nt)
            #pragma unroll
            for (int e = 0; e < 4; ++e)
                lds_o[(w * 16 + 4 * g + e) * 72 + nt * 16 + lc] = oacc[nt][e];
        __syncthreads();
        #pragma unroll
        for (int j = 0; j < 4; ++j) {
            const int row = j * 16 + (tid >> 4);     // 0..63
            const int col = (tid & 15) * 4;          // 0..60
            f32x4 v = *(f32x4*)&lds_o[row * 72 + col];
            __builtin_nontemporal_store(v, (f32x4*)(outb + (size_t)row * DH + col));
        }
    }
}

// ---- fallback (R2 kernel verbatim, used only if d_ws is too small) ----
__global__ __launch_bounds__(256, 3)
void sdpa_fallback(const float* __restrict__ Q, const float* __restrict__ K,
                   const float* __restrict__ V, float* __restrict__ out,
                   float* __restrict__ attn)
{
    __shared__ __align__(16) short lk[2][KT][72];
    __shared__ __align__(16) short lv[2][DH * 72];
    __shared__ __align__(16) short lp[4][16][72];

    const int tid = threadIdx.x;
    const int w = tid >> 6, lane = tid & 63, g = lane >> 4, lc = lane & 15;
    const int bid = (int)blockIdx.x;
    const int wg = (bid & 7) * 256 + (bid >> 3);
    const int qt = wg & 31, bh = wg >> 5;

    const float*  Qb  = Q + ((size_t)bh * SLEN + qt * 64) * DH;
    const float4* Kb4 = (const float4*)(K + (size_t)bh * SLEN * DH);
    const float4* Vb4 = (const float4*)(V + (size_t)bh * SLEN * DH);
    float* outb  = out  + ((size_t)bh * SLEN + qt * 64) * DH;
    float* attnb = attn + ((size_t)bh * SLEN + qt * 64) * SLEN;

    const int sr = (tid >> 4);
    const int sc = (tid & 15) * 4;

    bf16x8 qf[2];
    {
        const float* qsrc = Qb + (w * 16 + lc) * DH + g * 8;
        #pragma unroll
        for (int s = 0; s < 2; ++s)
            #pragma unroll
            for (int j = 0; j < 8; ++j)
                qf[s][j] = f2bf(qsrc[s * 32 + j] * 0.125f);
    }

    float lsum[4] = {0.f, 0.f, 0.f, 0.f};
    {
        float4 kr[4];
        #pragma unroll
        for (int q4 = 0; q4 < 4; ++q4) kr[q4] = Kb4[q4 * 256 + tid];
        #pragma unroll
        for (int q4 = 0; q4 < 4; ++q4) {
            short4 s4 = { f2bf(kr[q4].x), f2bf(kr[q4].y), f2bf(kr[q4].z), f2bf(kr[q4].w) };
            *(short4*)&lk[0][q4 * 16 + sr][sc] = s4;
        }
    }
    __syncthreads();
    for (int t = 0; t < NTL; ++t) {
        float4 kr[4];
        const bool pre = (t + 1 < NTL);
        if (pre) {
            const float4* src = Kb4 + (size_t)(t + 1) * 1024;
            #pragma unroll
            for (int q4 = 0; q4 < 4; ++q4) kr[q4] = src[q4 * 256 + tid];
        }
        f32x4 acc[4];
        #pragma unroll
        for (int nt = 0; nt < 4; ++nt) acc[nt] = (f32x4){0.f,0.f,0.f,0.f};
        #pragma unroll
        for (int s = 0; s < 2; ++s)
            #pragma unroll
            for (int nt = 0; nt < 4; ++nt) {
                bf16x8 kf = *(const bf16x8*)&lk[t & 1][nt * 16 + lc][s * 32 + g * 8];
                acc[nt] = __builtin_amdgcn_mfma_f32_16x16x32_bf16(qf[s], kf, acc[nt], 0, 0, 0);
            }
        #pragma unroll
        for (int nt = 0; nt < 4; ++nt)
            #pragma unroll
            for (int e = 0; e < 4; ++e)
                lsum[e] += __expf(acc[nt][e]);
        if (pre) {
            #pragma unroll
            for (int q4 = 0; q4 < 4; ++q4) {
                short4 s4 = { f2bf(kr[q4].x), f2bf(kr[q4].y), f2bf(kr[q4].z), f2bf(kr[q4].w) };
                *(short4*)&lk[(t + 1) & 1][q4 * 16 + sr][sc] = s4;
            }
        }
        __syncthreads();
    }
    float c2[4];
    #pragma unroll
    for (int e = 0; e < 4; ++e) {
        float s = lsum[e];
        s += __shfl_xor(s, 1); s += __shfl_xor(s, 2);
        s += __shfl_xor(s, 4); s += __shfl_xor(s, 8);
        c2[e] = -__logf(s);
    }
    f32x4 oacc[4];
    #pragma unroll
    for (int nt = 0; nt < 4; ++nt) oacc[nt] = (f32x4){0.f,0.f,0.f,0.f};
    {
        float4 kr[4], vr[4];
        #pragma unroll
        for (int q4 = 0; q4 < 4; ++q4) { kr[q4] = Kb4[q4 * 256 + tid]; vr[q4] = Vb4[q4 * 256 + tid]; }
        #pragma unroll
        for (int q4 = 0; q4 < 4; ++q4) {
            short4 s4 = { f2bf(kr[q4].x), f2bf(kr[q4].y), f2bf(kr[q4].z), f2bf(kr[q4].w) };
            *(short4*)&lk[0][q4 * 16 + sr][sc] = s4;
            float fv[4] = { vr[q4].x, vr[q4].y, vr[q4].z, vr[q4].w };
            #pragma unroll
            for (int j = 0; j < 4; ++j) {
                int d = sc + j;
                int idx = (d * 72 + q4 * 16 + sr) ^ (((d >> 3) & 7) << 3);
                lv[0][idx] = f2bf(fv[j]);
            }
        }
    }
    __syncthreads();
    for (int t = 0; t < NTL; ++t) {
        float4 kr[4], vr[4];
        const bool pre = (t + 1 < NTL);
        if (pre) {
            const float4* ks = Kb4 + (size_t)(t + 1) * 1024;
            const float4* vs = Vb4 + (size_t)(t + 1) * 1024;
            #pragma unroll
            for (int q4 = 0; q4 < 4; ++q4) { kr[q4] = ks[q4 * 256 + tid]; vr[q4] = vs[q4 * 256 + tid]; }
        }
        f32x4 acc[4];
        #pragma unroll
        for (int nt = 0; nt < 4; ++nt) acc[nt] = (f32x4){0.f,0.f,0.f,0.f};
        #pragma unroll
        for (int s = 0; s < 2; ++s)
            #pragma unroll
            for (int nt = 0; nt < 4; ++nt) {
                bf16x8 kf = *(const bf16x8*)&lk[t & 1][nt * 16 + lc][s * 32 + g * 8];
                acc[nt] = __builtin_amdgcn_mfma_f32_16x16x32_bf16(qf[s], kf, acc[nt], 0, 0, 0);
            }
        #pragma unroll
        for (int nt = 0; nt < 4; ++nt)
            #pragma unroll
            for (int e = 0; e < 4; ++e) {
                float p = __expf(acc[nt][e] + c2[e]);
                attnb[(size_t)(w * 16 + 4 * g + e) * SLEN + t * KT + nt * 16 + lc] = p;
                lp[w][4 * g + e][nt * 16 + lc] = f2bf(p);
            }
        const short* lvb = lv[t & 1];
        #pragma unroll
        for (int kc = 0; kc < 2; ++kc) {
            bf16x8 pf = *(const bf16x8*)&lp[w][lc][kc * 32 + g * 8];
            #pragma unroll
            for (int nt = 0; nt < 4; ++nt) {
                int d0 = nt * 16 + lc;
                int idx = (d0 * 72 + kc * 32 + g * 8) ^ (((d0 >> 3) & 7) << 3);
                bf16x8 vfrag = *(const bf16x8*)&lvb[idx];
                oacc[nt] = __builtin_amdgcn_mfma_f32_16x16x32_bf16(pf, vfrag, oacc[nt], 0, 0, 0);
            }
        }
        if (pre) {
            #pragma unroll
            for (int q4 = 0; q4 < 4; ++q4) {
                short4 s4 = { f2bf(kr[q4].x), f2bf(kr[q4].y), f2bf(kr[q4].z), f2bf(kr[q4].w) };
                *(short4*)&lk[(t + 1) & 1][q4 * 16 + sr][sc] = s4;
                float fv[4] = { vr[q4].x, vr[q4].y, vr[q4].z, vr[q4].w };
                #pragma unroll
                for (int j = 0; j < 4; ++j) {
                    int d = sc + j;
                    int idx = (d * 72 + q4 * 16 + sr) ^ (((d >> 3) & 7) << 3);
                    lv[(t + 1) & 1][idx] = f2bf(fv[j]);
                }
            }
        }
        __syncthreads();
    }
    #pragma unroll
    for (int nt = 0; nt < 4; ++nt)
        #pragma unroll
        for (int e = 0; e < 4; ++e)
            outb[(w * 16 + 4 * g + e) * DH + nt * 16 + lc] = oacc[nt][e];
}

extern "C" void kernel_launch(void* const* d_in, const int* in_sizes, int n_in,
                              void* d_out, int out_size, void* d_ws, size_t ws_size,
                              hipStream_t stream) {
    const float* Q = (const float*)d_in[0];
    const float* K = (const float*)d_in[1];
    const float* V = (const float*)d_in[2];
    float* out  = (float*)d_out;
    float* attn = out + (size_t)NBH * SLEN * DH;   // out first, then attn (return order)

    const size_t nelem = (size_t)NBH * SLEN * DH;  // 8388608 per tensor
    if (ws_size >= 2 * nelem * sizeof(short)) {
        short* Kw = (short*)d_ws;
        short* Vt = Kw + nelem;
        conv_kernel<<<dim3(2048, 2), dim3(256), 0, stream>>>(K, V, Kw, Vt);
        sdpa_main<<<dim3(2048), dim3(256), 0, stream>>>(Q, Kw, Vt, out, attn);
    } else {
        sdpa_fallback<<<dim3(2048), dim3(256), 0, stream>>>(Q, K, V, out, attn);
    }
}